// Round 9
// baseline (120.235 us; speedup 1.0000x reference)
//
#include <hip/hip_runtime.h>
#include <hip/hip_bf16.h>

// DLRM forward, 2 dispatches: wconv + block-local mega kernel.
// 128 blocks x 16 batch rows; whole network per block; activations in LDS;
// weights (bf16, pre-transposed) streamed from L2 per-lane; no grid sync.

#define BATCH 2048
#define VOCAB 100000

typedef __attribute__((ext_vector_type(8))) __bf16 bf16x8;
typedef __attribute__((ext_vector_type(4))) float f32x4;
typedef __hip_bfloat16 bf16;

#define MFMA __builtin_amdgcn_mfma_f32_16x16x32_bf16

// ---------------------------------------------------------------------------
// Weight convert+transpose: dst[n][kp] = bf16(src[k][n]), zero-pad k>=K. (R3)
// ---------------------------------------------------------------------------
struct WConvArgs {
    const float* src[6];
    bf16*        dst[6];
    int K[6], N[6], Kp[6], t0[7];
};

__global__ __launch_bounds__(256) void wconv_kernel(WConvArgs a)
{
    __shared__ float Ts[32][33];
    int w = 0;
    while (w < 5 && (int)blockIdx.x >= a.t0[w + 1]) ++w;
    const int rel = blockIdx.x - a.t0[w];
    const int K = a.K[w], N = a.N[w], Kp = a.Kp[w];
    const int nbn = N >> 5;
    const int tk = rel / nbn, tn = rel % nbn;
    const int tx = threadIdx.x & 31, ty = threadIdx.x >> 5;

    const float* src = a.src[w];
    bf16* dst = a.dst[w];

#pragma unroll
    for (int rr = 0; rr < 4; ++rr) {
        const int k = tk * 32 + ty + rr * 8;
        const int n = tn * 32 + tx;
        Ts[ty + rr * 8][tx] = (k < K) ? src[(size_t)k * N + n] : 0.f;
    }
    __syncthreads();
#pragma unroll
    for (int rr = 0; rr < 4; ++rr) {
        const int n = tn * 32 + ty + rr * 8;
        const int kp = tk * 32 + tx;
        dst[(size_t)n * Kp + kp] = __float2bfloat16(Ts[tx][ty + rr * 8]);
    }
}

// ---------------------------------------------------------------------------
// Tall GEMM layer: out[16][N] = relu(act[16][K] @ Wt[N][K]^T + bias).
// act in LDS (padded stride), Wt in global (L2-hot). 4 waves split N.
// Per wave: NREP 16-col fragments; K-loop has NO barriers.
// ---------------------------------------------------------------------------
template<int KSTEPS, int NREP>
__device__ __forceinline__ void layer(
    const bf16* actL, int strideA,
    const bf16* __restrict__ Wt, const float* __restrict__ bias,
    bf16* outL, int strideO,
    int wid, int lr, int q)
{
    constexpr int K = KSTEPS * 32;
    const int n0 = wid * NREP * 16;

    const bf16* wp[NREP];
#pragma unroll
    for (int n = 0; n < NREP; ++n)
        wp[n] = Wt + (size_t)(n0 + n * 16 + lr) * K + q * 8;
    const bf16* ap = actL + lr * strideA + q * 8;

    f32x4 acc[NREP] = {};
#pragma unroll 4
    for (int ks = 0; ks < KSTEPS; ++ks) {
        const bf16x8 af = *(const bf16x8*)(ap + ks * 32);
#pragma unroll
        for (int n = 0; n < NREP; ++n) {
            const bf16x8 bv = *(const bf16x8*)(wp[n] + ks * 32);
            acc[n] = MFMA(af, bv, acc[n], 0, 0, 0);
        }
    }

    // D layout: col = lane&15, row = (lane>>4)*4 + i
#pragma unroll
    for (int n = 0; n < NREP; ++n) {
        const int col = n0 + n * 16 + lr;
        const float bv = bias[col];
#pragma unroll
        for (int i = 0; i < 4; ++i) {
            float v = fmaxf(acc[n][i] + bv, 0.f);
            outL[(q * 4 + i) * strideO + col] = __float2bfloat16(v);
        }
    }
}

// ---------------------------------------------------------------------------
// Mega kernel: one block = 16 batch rows, entire network.
// LDS: T[16][32][72] bf16 (feats: 0=bot, 1..26=emb; reused as r0[16][1032]),
//      bufA[16][264], bufB[16][520] (h0 / R(456) / r1), rsum[4][16].
// ---------------------------------------------------------------------------
__global__ __launch_bounds__(256, 1) void mega(
    const float* __restrict__ dense, const int* __restrict__ cat,
    const float* __restrict__ tables,
    const bf16* __restrict__ bw0t, const float* __restrict__ bb0,
    const bf16* __restrict__ bw1t, const float* __restrict__ bb1,
    const bf16* __restrict__ bw2t, const float* __restrict__ bb2,
    const bf16* __restrict__ tw0t, const float* __restrict__ tb0,
    const bf16* __restrict__ tw1t, const float* __restrict__ tb1,
    const bf16* __restrict__ tw2t, const float* __restrict__ tb2,
    const float* __restrict__ tw3, const float* __restrict__ tb3,
    float* __restrict__ out)
{
    __shared__ __align__(16) bf16 T[16 * 32 * 72];   // 73728 B (also r0)
    __shared__ __align__(16) bf16 bufA[16 * 264];    //  8448 B
    __shared__ __align__(16) bf16 bufB[16 * 520];    // 16640 B
    __shared__ float rsum[4][16];

    const int t   = threadIdx.x;
    const int b0  = blockIdx.x * 16;
    const int wid = t >> 6, lane = t & 63;
    const int lr  = lane & 15, q = lane >> 4;

    // ---- stage dense -> bufA [16][40] bf16, k-padded to 32 ----
    for (int i = t; i < 16 * 32; i += 256) {
        const int r = i >> 5, c = i & 31;
        const float v = (c < 13) ? dense[(size_t)(b0 + r) * 13 + c] : 0.f;
        bufA[r * 40 + c] = __float2bfloat16(v);
    }
    __syncthreads();

    // ---- L0: [16][32] @ bw0t[512][32] -> bufB h0 [16][520] ----
    layer<1, 8>(bufA, 40, bw0t, bb0, bufB, 520, wid, lr, q);
    __syncthreads();

    // ---- L1: h0 @ bw1t[256][512] -> bufA h1 [16][264] ----
    layer<16, 4>(bufB, 520, bw1t, bb1, bufA, 264, wid, lr, q);
    __syncthreads();

    // ---- gather: 416 table rows -> T[r][1+j][.] bf16 ----
    for (int task = t; task < 416 * 16; task += 256) {
        const int g = task >> 4, c4 = task & 15;
        const int r = g / 26, j = g - r * 26;
        const int idx = cat[(b0 + r) * 26 + j];
        const float4 v =
            *(const float4*)&tables[((size_t)j * VOCAB + idx) * 64 + c4 * 4];
        union { bf16 h[4]; uint2 u; } pk;
        pk.h[0] = __float2bfloat16(v.x); pk.h[1] = __float2bfloat16(v.y);
        pk.h[2] = __float2bfloat16(v.z); pk.h[3] = __float2bfloat16(v.w);
        *(uint2*)&T[(r * 32 + 1 + j) * 72 + c4 * 4] = pk.u;
    }

    // ---- bot: h1 @ bw2t[64][256] -> T[r][0][.] (stride 32*72) ----
    layer<8, 1>(bufA, 264, bw2t, bb2, T, 32 * 72, wid, lr, q);

    // ---- zero R[r][415..447] (K-pad for top0) ----
    for (int i = t; i < 16 * 33; i += 256) {
        const int r = i / 33, c = i % 33;
        bufB[r * 456 + 415 + c] = __float2bfloat16(0.f);
    }
    __syncthreads();

    // ---- copy bot -> R[r][0..63] ----
    for (int i = t; i < 16 * 64; i += 256) {
        const int r = i >> 6, c = i & 63;
        bufB[r * 456 + c] = T[r * (32 * 72) + c];
    }

    // ---- gram interaction: per wave 4 rows; G = T_r @ T_r^T via MFMA ----
    {
#pragma unroll
        for (int rr = 0; rr < 4; ++rr) {
            const int r = wid * 4 + rr;
            const bf16* Tr = T + r * (32 * 72);
            f32x4 g00 = {}, g10 = {}, g11 = {};
#pragma unroll
            for (int ks = 0; ks < 2; ++ks) {
                const bf16x8 a0 = *(const bf16x8*)(Tr + lr * 72 + ks * 32 + q * 8);
                const bf16x8 a1 = *(const bf16x8*)(Tr + (16 + lr) * 72 + ks * 32 + q * 8);
                g00 = MFMA(a0, a0, g00, 0, 0, 0);
                g10 = MFMA(a1, a0, g10, 0, 0, 0);
                g11 = MFMA(a1, a1, g11, 0, 0, 0);
            }
            // D: row = ro + q*4+i, col = co + lr; keep row<27 && col<row
#pragma unroll
            for (int i = 0; i < 4; ++i) {
                {   const int row = q * 4 + i, col = lr;          // (0,0)
                    if (col < row) {
                        const int p = row * (row - 1) / 2 + col;
                        bufB[r * 456 + 64 + p] = __float2bfloat16(g00[i]);
                    } }
                {   const int row = 16 + q * 4 + i, col = lr;     // (1,0)
                    if (row < 27) {
                        const int p = row * (row - 1) / 2 + col;
                        bufB[r * 456 + 64 + p] = __float2bfloat16(g10[i]);
                    } }
                {   const int row = 16 + q * 4 + i, col = 16 + lr;// (1,1)
                    if (row < 27 && col < row) {
                        const int p = row * (row - 1) / 2 + col;
                        bufB[r * 456 + 64 + p] = __float2bfloat16(g11[i]);
                    } }
            }
        }
    }
    __syncthreads();

    // ---- top0: R[16][448] @ tw0t[1024][448] -> r0 (T region) [16][1032] ----
    bf16* r0 = T;
    layer<14, 16>(bufB, 456, tw0t, tb0, r0, 1032, wid, lr, q);
    __syncthreads();

    // ---- top1: r0 @ tw1t[512][1024] -> bufB r1 [16][520] ----
    layer<32, 8>(r0, 1032, tw1t, tb1, bufB, 520, wid, lr, q);
    __syncthreads();

    // ---- top2 (K=512, N=256) + fused sigmoid dot ----
    {
        constexpr int KST = 16, NR = 4;
        constexpr int K = 512;
        const int n0 = wid * 64;
        const bf16* wp[NR];
#pragma unroll
        for (int n = 0; n < NR; ++n)
            wp[n] = tw2t + (size_t)(n0 + n * 16 + lr) * K + q * 8;
        const bf16* ap = bufB + lr * 520 + q * 8;

        f32x4 acc[NR] = {};
#pragma unroll 4
        for (int ks = 0; ks < KST; ++ks) {
            const bf16x8 af = *(const bf16x8*)(ap + ks * 32);
#pragma unroll
            for (int n = 0; n < NR; ++n)
                acc[n] = MFMA(af, *(const bf16x8*)(wp[n] + ks * 32), acc[n], 0, 0, 0);
        }

        float s[4] = {0.f, 0.f, 0.f, 0.f};
#pragma unroll
        for (int n = 0; n < NR; ++n) {
            const int col = n0 + n * 16 + lr;
            const float bv = tb2[col];
            const float wv = tw3[col];
#pragma unroll
            for (int i = 0; i < 4; ++i)
                s[i] += fmaxf(acc[n][i] + bv, 0.f) * wv;
        }
#pragma unroll
        for (int i = 0; i < 4; ++i) {
            s[i] += __shfl_xor(s[i], 1);
            s[i] += __shfl_xor(s[i], 2);
            s[i] += __shfl_xor(s[i], 4);
            s[i] += __shfl_xor(s[i], 8);
        }
        if (lr == 0) {
#pragma unroll
            for (int i = 0; i < 4; ++i) rsum[wid][q * 4 + i] = s[i];
        }
        __syncthreads();
        if (t < 16) {
            const float tot = rsum[0][t] + rsum[1][t] + rsum[2][t] + rsum[3][t];
            out[b0 + t] = 1.f / (1.f + expf(-(tot + tb3[0])));
        }
    }
}

// ---------------------------------------------------------------------------
extern "C" void kernel_launch(void* const* d_in, const int* in_sizes, int n_in,
                              void* d_out, int out_size, void* d_ws, size_t ws_size,
                              hipStream_t stream)
{
    const float* dense   = (const float*)d_in[0];
    const int*   cat_idx = (const int*)  d_in[1];
    const float* tables  = (const float*)d_in[2];
    const float* bw0 = (const float*)d_in[3];
    const float* bb0 = (const float*)d_in[4];
    const float* bw1 = (const float*)d_in[5];
    const float* bb1 = (const float*)d_in[6];
    const float* bw2 = (const float*)d_in[7];
    const float* bb2 = (const float*)d_in[8];
    const float* tw0 = (const float*)d_in[9];
    const float* tb0 = (const float*)d_in[10];
    const float* tw1 = (const float*)d_in[11];
    const float* tb1 = (const float*)d_in[12];
    const float* tw2 = (const float*)d_in[13];
    const float* tb2 = (const float*)d_in[14];
    const float* tw3 = (const float*)d_in[15];
    const float* tb3 = (const float*)d_in[16];

    bf16* p = (bf16*)d_ws;
    bf16* bw0t = p; p += 512 * 32;
    bf16* bw1t = p; p += 256 * 512;
    bf16* bw2t = p; p += 64 * 256;
    bf16* tw0t = p; p += 1024 * 448;
    bf16* tw1t = p; p += 512 * 1024;
    bf16* tw2t = p; p += 256 * 512;
    float* out = (float*)d_out;

    WConvArgs wa;
    wa.src[0] = bw0;  wa.dst[0] = bw0t; wa.K[0] = 13;   wa.N[0] = 512;  wa.Kp[0] = 32;
    wa.src[1] = bw1;  wa.dst[1] = bw1t; wa.K[1] = 512;  wa.N[1] = 256;  wa.Kp[1] = 512;
    wa.src[2] = bw2;  wa.dst[2] = bw2t; wa.K[2] = 256;  wa.N[2] = 64;   wa.Kp[2] = 256;
    wa.src[3] = tw0;  wa.dst[3] = tw0t; wa.K[3] = 415;  wa.N[3] = 1024; wa.Kp[3] = 448;
    wa.src[4] = tw1;  wa.dst[4] = tw1t; wa.K[4] = 1024; wa.N[4] = 512;  wa.Kp[4] = 1024;
    wa.src[5] = tw2;  wa.dst[5] = tw2t; wa.K[5] = 512;  wa.N[5] = 256;  wa.Kp[5] = 512;
    int tiles = 0;
    for (int w = 0; w < 6; ++w) {
        wa.t0[w] = tiles;
        tiles += (wa.Kp[w] >> 5) * (wa.N[w] >> 5);
    }
    wa.t0[6] = tiles;

    wconv_kernel<<<tiles, 256, 0, stream>>>(wa);

    mega<<<BATCH / 16, 256, 0, stream>>>(
        dense, cat_idx, tables,
        bw0t, bb0, bw1t, bb1, bw2t, bb2,
        tw0t, tb0, tw1t, tb1, tw2t, tb2, tw3, tb3, out);
}